// Round 12
// baseline (589.550 us; speedup 1.0000x reference)
//
#include <hip/hip_runtime.h>
#include <hip/hip_bf16.h>
#include <math.h>

#define BB 2
#define CC 128
#define HH 60
#define WW 108
#define HWN (HH*WW)
#define GR 160                // zeroed guard rows between batches (>= 48 tail + 109 halo)
#define RSTR (HWN + GR)       // guarded row stride per batch

typedef __attribute__((ext_vector_type(8))) short s16x8;
typedef __attribute__((ext_vector_type(4))) float f32x4;
typedef __attribute__((ext_vector_type(4))) unsigned int u32x4;

__device__ __forceinline__ unsigned short f2b(float f) {
    union { float f; unsigned int u; } v; v.f = f;
    unsigned int r = (v.u + 0x7FFFu + ((v.u >> 16) & 1u)) >> 16;
    return (unsigned short)r;
}
__device__ __forceinline__ float b2f(unsigned short b) {
    union { unsigned int u; float f; } v; v.u = ((unsigned int)b) << 16;
    return v.f;
}

// ---------------------------------------------------------------------------
// Zero the guard rows of a guarded channel-last buffer (base pointer = alloc
// start, NOT pre-offset). Guard blocks of GR rows at row g*RSTR, g=0..BB.
// ---------------------------------------------------------------------------
__global__ void zero_guard_k(unsigned short* __restrict__ p, int C) {
    int idx = blockIdx.x * 256 + threadIdx.x;
    int cw = C / 8;
    int total = (BB + 1) * GR * cw;
    if (idx >= total) return;
    int g  = idx / (GR * cw);
    int rr = idx % (GR * cw);
    int row = g * RSTR + rr / cw;
    int c8  = (rr % cw) * 8;
    s16x8 z = {};
    *(s16x8*)(p + (size_t)row * C + c8) = z;
}

// ---------------------------------------------------------------------------
// fmap [B][128][HW] f32 -> [B][HW][128] f32 (channel-last, for lookup)
// ---------------------------------------------------------------------------
__global__ void f2cl_k(const float* __restrict__ in, float* __restrict__ out) {
    int n = blockIdx.x * 64 + threadIdx.x;
    int b = blockIdx.y;
    if (n >= HWN) return;
    const float* ip = in + (size_t)b * CC * HWN + n;
    float* op = out + ((size_t)b * HWN + n) * CC;
    for (int c0 = 0; c0 < CC; c0 += 4) {
        float4 o;
        o.x = ip[(size_t)(c0 + 0) * HWN];
        o.y = ip[(size_t)(c0 + 1) * HWN];
        o.z = ip[(size_t)(c0 + 2) * HWN];
        o.w = ip[(size_t)(c0 + 3) * HWN];
        *(float4*)(op + c0) = o;
    }
}

// ---------------------------------------------------------------------------
// ft [B][112][HW] f32 -> guarded [*][128] bf16 (pad ch 112..127 zero)
// out is pre-offset to interior row 0.
// ---------------------------------------------------------------------------
__global__ void ft2cl_k(const float* __restrict__ ft, unsigned short* __restrict__ out) {
    int n = blockIdx.x * 64 + threadIdx.x;
    int b = blockIdx.y;
    if (n >= HWN) return;
    const float* ip = ft + (size_t)b * 112 * HWN + n;
    unsigned short* op = out + ((size_t)b * RSTR + n) * 128;
    for (int c0 = 0; c0 < 112; c0 += 8) {
        s16x8 o;
        #pragma unroll
        for (int j = 0; j < 8; j++) o[j] = (short)f2b(ip[(size_t)(c0 + j) * HWN]);
        *(s16x8*)(op + c0) = o;
    }
    s16x8 z = {};
    *(s16x8*)(op + 112) = z;
    *(s16x8*)(op + 120) = z;
}

// ---------------------------------------------------------------------------
// 2x2 avg pool on channel-last f32 maps
// ---------------------------------------------------------------------------
__global__ void pool_k(const float* __restrict__ in, float* __restrict__ out,
                       int Hi, int Wi, int Ho, int Wo) {
    int bp = blockIdx.x;
    int b  = bp / (Ho * Wo);
    int p  = bp % (Ho * Wo);
    int yo = p / Wo, xo = p % Wo;
    int c  = threadIdx.x;
    const float* i0 = in + (((size_t)b * Hi + 2 * yo) * Wi + 2 * xo) * CC;
    float v = i0[c] + i0[CC + c] + i0[(size_t)Wi * CC + c] + i0[(size_t)Wi * CC + CC + c];
    out[(((size_t)b * Ho + yo) * Wo + xo) * CC + c] = 0.25f * v;
}

// ---------------------------------------------------------------------------
// Correlation pyramid lookup -> guarded corr_cl [*][416] bf16 (pre-offset).
// grid: (B*HW, 2) block 256. blockIdx.y = dir; wave (tid>>6) = level.
// ---------------------------------------------------------------------------
__global__ void lookup_k(const float* __restrict__ f0cl, const float* __restrict__ f1cl,
                         const float* __restrict__ f0p1, const float* __restrict__ f0p2,
                         const float* __restrict__ f0p3,
                         const float* __restrict__ f1p1, const float* __restrict__ f1p2,
                         const float* __restrict__ f1p3,
                         const float* __restrict__ flow0, const float* __restrict__ flow1,
                         const float* __restrict__ embt, unsigned short* __restrict__ corr_cl) {
    int bn = blockIdx.x;
    int b  = bn / HWN;
    int n  = bn % HWN;
    int y  = n / WW, x = n % WW;
    int dir = blockIdx.y;
    int tid = threadIdx.x;
    int lane = tid & 63;
    int lvl  = tid >> 6;

    __shared__ __align__(16) float fvec[CC];
    __shared__ float dsh[4][64];

    const float* fsrc = (dir == 0) ? f0cl : f1cl;
    if (tid < 128) fvec[tid] = fsrc[(size_t)bn * CC + tid];

    float e  = embt[b];
    float sc = (dir == 0) ? (1.0f / e) : (1.0f / (1.0f - e));
    const float* fl = (dir == 0) ? flow1 : flow0;
    float fx = fl[((size_t)(b * 2 + 0) * HH + y) * WW + x];
    float fy = fl[((size_t)(b * 2 + 1) * HH + y) * WW + x];
    float inv = 1.0f / (float)(1 << lvl);
    float cx = ((float)x + fx * sc) * inv;
    float cy = ((float)y + fy * sc) * inv;
    float fx0 = floorf(cx), fy0 = floorf(cy);
    float wx = cx - fx0, wy = cy - fy0;
    int ix0 = (int)fx0, iy0 = (int)fy0;

    const float* map;
    if (dir == 0) map = (lvl == 0) ? f1cl : (lvl == 1) ? f1p1 : (lvl == 2) ? f1p2 : f1p3;
    else          map = (lvl == 0) ? f0cl : (lvl == 1) ? f0p1 : (lvl == 2) ? f0p2 : f0p3;
    int Hl = (lvl == 0) ? 60 : (lvl == 1) ? 30 : (lvl == 2) ? 15 : 7;
    int Wl = (lvl == 0) ? 108 : (lvl == 1) ? 54 : (lvl == 2) ? 27 : 13;

    int g   = lane >> 3;   // window col
    int sub = lane & 7;    // 16B chunk within column

    __syncthreads();

    const float4* fv4 = (const float4*)fvec;
    #pragma unroll
    for (int p = 0; p < 8; p++) {
        int c  = p * 8 + g;
        int xi = ix0 - 3 + g;
        int yi = iy0 - 3 + p;
        float part = 0.0f;
        if ((unsigned)xi < (unsigned)Wl && (unsigned)yi < (unsigned)Hl) {
            const float4* cp = (const float4*)(map + (((size_t)b * Hl + yi) * Wl + xi) * CC);
            #pragma unroll
            for (int it = 0; it < 4; it++) {
                float4 a = cp[it * 8 + sub];
                float4 f = fv4[it * 8 + sub];
                part += a.x * f.x + a.y * f.y + a.z * f.z + a.w * f.w;
            }
        }
        part += __shfl_xor(part, 1);
        part += __shfl_xor(part, 2);
        part += __shfl_xor(part, 4);
        if (sub == 0) dsh[lvl][c] = part * 0.08838834764831845f;  // 1/sqrt(128)
    }
    __syncthreads();

    if (lane < 49) {
        int r0 = lane / 7, c0 = lane % 7;
        float d00 = dsh[lvl][r0 * 8 + c0],       d01 = dsh[lvl][r0 * 8 + c0 + 1];
        float d10 = dsh[lvl][(r0 + 1) * 8 + c0], d11 = dsh[lvl][(r0 + 1) * 8 + c0 + 1];
        float val = d00 * (1.0f - wx) * (1.0f - wy) + d01 * wx * (1.0f - wy)
                  + d10 * (1.0f - wx) * wy          + d11 * wx * wy;
        int ch = dir * 196 + lvl * 49 + lane;
        corr_cl[((size_t)b * RSTR + n) * 416 + ch] = f2b(val);
    }
}

// ---------------------------------------------------------------------------
// Pack conv weights into MFMA B-fragment layout:
// chunk idx = ((tap*KSTEPS+ks)*TOTOCT+oct)*64+lane; 8 bf16/chunk:
// oc = oct*16+(lane&15), ic = ks*32+(lane>>4)*8+j.
// ---------------------------------------------------------------------------
__global__ void packw_k(const float* __restrict__ w1, const float* __restrict__ w2,
                        int OC1, int OCreal, int Cin, int TAPS, int KSTEPS, int TOTOCT,
                        unsigned short* __restrict__ out) {
    int idx = blockIdx.x * 256 + threadIdx.x;
    int total = TAPS * KSTEPS * TOTOCT * 64;
    if (idx >= total) return;
    int lane = idx & 63;
    int rest = idx >> 6;
    int oct  = rest % TOTOCT;
    int rk   = rest / TOTOCT;
    int ks   = rk % KSTEPS;
    int tap  = rk / KSTEPS;
    int oc = oct * 16 + (lane & 15);
    int kb = ks * 32 + (lane >> 4) * 8;
    s16x8 o;
    #pragma unroll
    for (int j = 0; j < 8; j++) {
        int ic = kb + j;
        float val = 0.0f;
        if (oc < OCreal && ic < Cin) {
            val = (oc < OC1) ? w1[((size_t)oc * Cin + ic) * TAPS + tap]
                             : w2[((size_t)(oc - OC1) * Cin + ic) * TAPS + tap];
        }
        o[j] = (short)f2b(val);
    }
    *(s16x8*)(out + (size_t)idx * 8) = o;
}

// ---------------------------------------------------------------------------
// MFMA implicit-GEMM conv. ks-outer/tap-inner. UNCONDITIONAL loads:
// y-halo reads land in zeroed guard rows; x-edge wrap is fixed by AND-ing the
// loaded regs with a precomputed per-(m,tap) keep mask (dx!=0 taps only).
// No exec-mask divergence in the inner loop -> loads batch & pipeline.
// gin/gout(OGUARD) are pre-offset to interior row 0 of guarded buffers.
// ACT: 0 none 1 relu 2 sigmoid 3 tanh. EPI: 0 bf16 CL, 1 bf16 CL x2, 2 f32 CF.
// ---------------------------------------------------------------------------
template<int NOCT, int MF, int TAPS, int KSTEPS, int NCS, int TOT, int ACT, int EPI, int OGUARD>
__launch_bounds__(256)
__global__ void convmf_k(const unsigned short* __restrict__ gin,
                         const unsigned short* __restrict__ wp,
                         const float* __restrict__ bias1, const float* __restrict__ bias2,
                         int OC1, int OCreal,
                         unsigned short* __restrict__ gout, int OCS, int ocoff,
                         unsigned short* __restrict__ gout2, int OCS2,
                         float* __restrict__ fout) {
    int lane = threadIdx.x & 63;
    int wv   = threadIdx.x >> 6;
    int ocg  = blockIdx.y;
    int b    = blockIdx.z;
    int p0   = (blockIdx.x * 4 + wv) * (MF * 16);
    int oct0 = ocg * NOCT;
    int arow = lane & 15;
    int koff = (lane >> 4) * 8;

    const unsigned short* ap[MF][TAPS];
    unsigned km[MF][TAPS];
    #pragma unroll
    for (int m = 0; m < MF; m++) {
        int pa = p0 + m * 16 + arow;
        int py = pa / WW, px = pa - py * WW;
        (void)py;
        #pragma unroll
        for (int tap = 0; tap < TAPS; tap++) {
            const int dy = (TAPS == 1) ? 0 : (tap / 3 - 1);
            const int dx = (TAPS == 1) ? 0 : (tap % 3 - 1);
            ap[m][tap] = gin + (ptrdiff_t)(b * RSTR + pa + dy * WW + dx) * NCS + koff;
            km[m][tap] = ((unsigned)(px + dx) < (unsigned)WW) ? 0xFFFFFFFFu : 0u;
        }
    }

    f32x4 acc[MF][NOCT];
    #pragma unroll
    for (int m = 0; m < MF; m++)
        #pragma unroll
        for (int t = 0; t < NOCT; t++) acc[m][t] = f32x4{0.f, 0.f, 0.f, 0.f};

    #pragma unroll
    for (int ks = 0; ks < KSTEPS; ks++) {
        #pragma unroll
        for (int tap = 0; tap < TAPS; tap++) {
            const int dx = (TAPS == 1) ? 0 : (tap % 3 - 1);
            s16x8 a[MF];
            #pragma unroll
            for (int m = 0; m < MF; m++) {
                a[m] = *(const s16x8*)(ap[m][tap] + ks * 32);
                if (dx != 0) {
                    u32x4 t = __builtin_bit_cast(u32x4, a[m]);
                    t &= km[m][tap];
                    a[m] = __builtin_bit_cast(s16x8, t);
                }
            }
            s16x8 bf[NOCT];
            const unsigned short* bpp = wp
                + ((size_t)(tap * KSTEPS + ks) * TOT + oct0) * 512 + (size_t)lane * 8;
            #pragma unroll
            for (int t = 0; t < NOCT; t++) bf[t] = *(const s16x8*)(bpp + (size_t)t * 512);
            #pragma unroll
            for (int m = 0; m < MF; m++)
                #pragma unroll
                for (int t = 0; t < NOCT; t++)
                    acc[m][t] = __builtin_amdgcn_mfma_f32_16x16x32_bf16(a[m], bf[t], acc[m][t], 0, 0, 0);
        }
    }

    int oc_l = lane & 15;
    #pragma unroll
    for (int t = 0; t < NOCT; t++) {
        int oc = (oct0 + t) * 16 + oc_l;
        float bs = 0.0f;
        if (oc < OCreal) bs = (oc < OC1) ? bias1[oc] : bias2[oc - OC1];
        #pragma unroll
        for (int m = 0; m < MF; m++) {
            int prow = p0 + m * 16 + (lane >> 4) * 4;
            #pragma unroll
            for (int r = 0; r < 4; r++) {
                int p = prow + r;
                if (p >= HWN) continue;
                float vv = acc[m][t][r] + bs;
                if (ACT == 1) vv = fmaxf(vv, 0.0f);
                else if (ACT == 2) vv = 1.0f / (1.0f + __expf(-vv));
                else if (ACT == 3) vv = tanhf(vv);
                if (EPI == 2) {
                    if (oc < OCreal) fout[((size_t)b * OCreal + oc) * HWN + p] = vv;
                } else {
                    unsigned short bvv = f2b(vv);
                    size_t row = (size_t)b * (OGUARD ? RSTR : HWN) + p;
                    gout[row * OCS + ocoff + oc] = bvv;
                    if (EPI == 1) gout2[((size_t)b * HWN + p) * OCS2 + oc] = bvv;
                }
            }
        }
    }
}

// ---------------------------------------------------------------------------
// flow conv (4->64, 3x3, relu), direct f32, writes guarded gi ch 448..511
// ---------------------------------------------------------------------------
__global__ void flowconv_k(const float* __restrict__ flow0, const float* __restrict__ flow1,
                           const float* __restrict__ w, const float* __restrict__ bias,
                           unsigned short* __restrict__ gi) {
    int n = blockIdx.x * 64 + threadIdx.x;
    int b = blockIdx.y;
    if (n >= HWN) return;
    int y = n / WW, x = n - y * WW;
    float v[36];
    for (int c = 0; c < 4; c++) {
        const float* pl = (c < 2) ? flow0 + ((size_t)b * 2 + c) * HWN
                                  : flow1 + ((size_t)b * 2 + (c - 2)) * HWN;
        #pragma unroll
        for (int dy = -1; dy <= 1; dy++)
            #pragma unroll
            for (int dx = -1; dx <= 1; dx++) {
                int yy = y + dy, xx = x + dx;
                v[c * 9 + (dy + 1) * 3 + (dx + 1)] =
                    (((unsigned)yy < (unsigned)HH) && ((unsigned)xx < (unsigned)WW))
                        ? pl[(size_t)yy * WW + xx] : 0.0f;
            }
    }
    unsigned short* op = gi + ((size_t)b * RSTR + n) * 512 + 448;
    for (int oc0 = 0; oc0 < 64; oc0 += 8) {
        s16x8 o;
        #pragma unroll
        for (int j = 0; j < 8; j++) {
            int oc = oc0 + j;
            const float* wpp = w + (size_t)oc * 36;
            float a = bias[oc];
            #pragma unroll
            for (int k = 0; k < 36; k++) a += wpp[k] * v[k];
            o[j] = (short)f2b(fmaxf(a, 0.0f));
        }
        *(s16x8*)(op + oc0) = o;
    }
}

// ---------------------------------------------------------------------------
// rh: guarded gi[ch 0..191] = r * h
// ---------------------------------------------------------------------------
__global__ void rh_k(const unsigned short* __restrict__ zr, const unsigned short* __restrict__ hs,
                     unsigned short* __restrict__ gi) {
    int idx = blockIdx.x * 256 + threadIdx.x;
    if (idx >= BB * HWN * 24) return;
    int n = idx / 24, c8 = (idx % 24) * 8;
    int b = n / HWN, nn = n - b * HWN;
    s16x8 r = *(const s16x8*)(zr + (size_t)n * 384 + 192 + c8);
    s16x8 h = *(const s16x8*)(hs + (size_t)n * 192 + c8);
    s16x8 o;
    #pragma unroll
    for (int j = 0; j < 8; j++)
        o[j] = (short)f2b(b2f((unsigned short)r[j]) * b2f((unsigned short)h[j]));
    *(s16x8*)(gi + ((size_t)b * RSTR + nn) * 512 + c8) = o;
}

// ---------------------------------------------------------------------------
// hnew: guarded gi[ch 0..191] = (1-z)*h + z*q
// ---------------------------------------------------------------------------
__global__ void hnew_k(const unsigned short* __restrict__ zr, const unsigned short* __restrict__ hs,
                       const unsigned short* __restrict__ q, unsigned short* __restrict__ gi) {
    int idx = blockIdx.x * 256 + threadIdx.x;
    if (idx >= BB * HWN * 24) return;
    int n = idx / 24, c8 = (idx % 24) * 8;
    int b = n / HWN, nn = n - b * HWN;
    s16x8 z = *(const s16x8*)(zr + (size_t)n * 384 + c8);
    s16x8 h = *(const s16x8*)(hs + (size_t)n * 192 + c8);
    s16x8 qq = *(const s16x8*)(q + (size_t)n * 192 + c8);
    s16x8 o;
    #pragma unroll
    for (int j = 0; j < 8; j++) {
        float zf = b2f((unsigned short)z[j]);
        o[j] = (short)f2b((1.0f - zf) * b2f((unsigned short)h[j]) + zf * b2f((unsigned short)qq[j]));
    }
    *(s16x8*)(gi + ((size_t)b * RSTR + nn) * 512 + c8) = o;
}

// ---------------------------------------------------------------------------
extern "C" void kernel_launch(void* const* d_in, const int* in_sizes, int n_in,
                              void* d_out, int out_size, void* d_ws, size_t ws_size,
                              hipStream_t stream) {
    const float* fmap0 = (const float*)d_in[0];
    const float* fmap1 = (const float*)d_in[1];
    const float* ft    = (const float*)d_in[2];
    const float* flow0 = (const float*)d_in[3];
    const float* flow1 = (const float*)d_in[4];
    const float* embt  = (const float*)d_in[5];
    const float* w_corr = (const float*)d_in[6];
    const float* b_corr = (const float*)d_in[7];
    const float* w_flow = (const float*)d_in[8];
    const float* b_flow = (const float*)d_in[9];
    const float* w_ctx  = (const float*)d_in[10];
    const float* b_ctx  = (const float*)d_in[11];
    const float* w_z    = (const float*)d_in[12];
    const float* b_z    = (const float*)d_in[13];
    const float* w_r    = (const float*)d_in[14];
    const float* b_r    = (const float*)d_in[15];
    const float* w_q    = (const float*)d_in[16];
    const float* b_q    = (const float*)d_in[17];
    const float* w_fh   = (const float*)d_in[18];
    const float* b_fh   = (const float*)d_in[19];
    const float* w_dh   = (const float*)d_in[20];
    const float* b_dh   = (const float*)d_in[21];
    float* out = (float*)d_out;

    char* ws = (char*)d_ws;
    size_t off = 0;
    auto alloc = [&](size_t bytes) { size_t o = off; off += (bytes + 255) & ~(size_t)255; return o; };

    const size_t GROWS = (size_t)GR + (size_t)BB * RSTR;   // guarded row count

    float* f0cl = (float*)(ws + alloc((size_t)BB * HWN * CC * 4));
    float* f1cl = (float*)(ws + alloc((size_t)BB * HWN * CC * 4));
    float* f0p1 = (float*)(ws + alloc((size_t)BB * 30 * 54 * CC * 4));
    float* f0p2 = (float*)(ws + alloc((size_t)BB * 15 * 27 * CC * 4));
    float* f0p3 = (float*)(ws + alloc((size_t)BB * 7 * 13 * CC * 4));
    float* f1p1 = (float*)(ws + alloc((size_t)BB * 30 * 54 * CC * 4));
    float* f1p2 = (float*)(ws + alloc((size_t)BB * 15 * 27 * CC * 4));
    float* f1p3 = (float*)(ws + alloc((size_t)BB * 7 * 13 * CC * 4));
    unsigned short* ftcl   = (unsigned short*)(ws + alloc(GROWS * 128 * 2));
    unsigned short* corrcl = (unsigned short*)(ws + alloc(GROWS * 416 * 2));
    unsigned short* gi     = (unsigned short*)(ws + alloc(GROWS * 512 * 2));
    unsigned short* hsep   = (unsigned short*)(ws + alloc((size_t)BB * HWN * 192 * 2));
    unsigned short* zrbuf  = (unsigned short*)(ws + alloc((size_t)BB * HWN * 384 * 2));
    unsigned short* qbuf   = (unsigned short*)(ws + alloc((size_t)BB * HWN * 192 * 2));
    unsigned short* wpzr   = (unsigned short*)(ws + alloc((size_t)9 * 16 * 24 * 64 * 8 * 2));
    unsigned short* wpq    = (unsigned short*)(ws + alloc((size_t)9 * 16 * 12 * 64 * 8 * 2));
    unsigned short* wpctx  = (unsigned short*)(ws + alloc((size_t)9 * 4 * 12 * 64 * 8 * 2));
    unsigned short* wpdh   = (unsigned short*)(ws + alloc((size_t)9 * 6 * 8 * 64 * 8 * 2));
    unsigned short* wpcorr = (unsigned short*)(ws + alloc((size_t)1 * 13 * 16 * 64 * 8 * 2));

    // interior-row-0 views of guarded buffers
    unsigned short* ftclG   = ftcl   + (size_t)GR * 128;
    unsigned short* corrclG = corrcl + (size_t)GR * 416;
    unsigned short* giG     = gi     + (size_t)GR * 512;

    // zero guard rows (deterministic every call; producers never touch guards)
    zero_guard_k<<<dim3(((BB + 1) * GR * (512 / 8) + 255) / 256), dim3(256), 0, stream>>>(gi, 512);
    zero_guard_k<<<dim3(((BB + 1) * GR * (128 / 8) + 255) / 256), dim3(256), 0, stream>>>(ftcl, 128);
    zero_guard_k<<<dim3(((BB + 1) * GR * (416 / 8) + 255) / 256), dim3(256), 0, stream>>>(corrcl, 416);

    // weight packing
    packw_k<<<dim3((9 * 16 * 24 * 64 + 255) / 256), dim3(256), 0, stream>>>(
        w_z, w_r, 192, 384, 512, 9, 16, 24, wpzr);
    packw_k<<<dim3((9 * 16 * 12 * 64 + 255) / 256), dim3(256), 0, stream>>>(
        w_q, w_q, 192, 192, 512, 9, 16, 12, wpq);
    packw_k<<<dim3((9 * 4 * 12 * 64 + 255) / 256), dim3(256), 0, stream>>>(
        w_ctx, w_ctx, 192, 192, 112, 9, 4, 12, wpctx);
    packw_k<<<dim3((9 * 6 * 8 * 64 + 255) / 256), dim3(256), 0, stream>>>(
        w_dh, w_fh, 112, 116, 192, 9, 6, 8, wpdh);
    packw_k<<<dim3((1 * 13 * 16 * 64 + 255) / 256), dim3(256), 0, stream>>>(
        w_corr, w_corr, 256, 256, 392, 1, 13, 16, wpcorr);

    // channel-last transposes + pyramids
    f2cl_k<<<dim3((HWN + 63) / 64, BB), dim3(64), 0, stream>>>(fmap0, f0cl);
    f2cl_k<<<dim3((HWN + 63) / 64, BB), dim3(64), 0, stream>>>(fmap1, f1cl);
    ft2cl_k<<<dim3((HWN + 63) / 64, BB), dim3(64), 0, stream>>>(ft, ftclG);
    pool_k<<<dim3(BB * 30 * 54), dim3(128), 0, stream>>>(f0cl, f0p1, 60, 108, 30, 54);
    pool_k<<<dim3(BB * 15 * 27), dim3(128), 0, stream>>>(f0p1, f0p2, 30, 54, 15, 27);
    pool_k<<<dim3(BB * 7 * 13),  dim3(128), 0, stream>>>(f0p2, f0p3, 15, 27, 7, 13);
    pool_k<<<dim3(BB * 30 * 54), dim3(128), 0, stream>>>(f1cl, f1p1, 60, 108, 30, 54);
    pool_k<<<dim3(BB * 15 * 27), dim3(128), 0, stream>>>(f1p1, f1p2, 30, 54, 15, 27);
    pool_k<<<dim3(BB * 7 * 13),  dim3(128), 0, stream>>>(f1p2, f1p3, 15, 27, 7, 13);

    // lookup -> guarded corr_cl bf16
    lookup_k<<<dim3(BB * HWN, 2), dim3(256), 0, stream>>>(
        f0cl, f1cl, f0p1, f0p2, f0p3, f1p1, f1p2, f1p3,
        flow0, flow1, embt, corrclG);

    // ffeat -> giG ch 448..511
    flowconv_k<<<dim3((HWN + 63) / 64, BB), dim3(64), 0, stream>>>(flow0, flow1, w_flow, b_flow, giG);

    // cfeat = relu(1x1 conv corrcl) -> giG ch 192..447  (MF=2, NOCT=2, 8 ocg)
    convmf_k<2, 2, 1, 13, 416, 16, 1, 0, 1><<<dim3(51, 8, BB), dim3(256), 0, stream>>>(
        corrclG, wpcorr, b_corr, b_corr, 256, 256, giG, 512, 192, nullptr, 0, nullptr);

    // h = tanh(ctx conv ftcl) -> giG ch 0..191 AND hsep  (MF=2, NOCT=3, 4 ocg)
    convmf_k<3, 2, 9, 4, 128, 12, 3, 1, 1><<<dim3(51, 4, BB), dim3(256), 0, stream>>>(
        ftclG, wpctx, b_ctx, b_ctx, 192, 192, giG, 512, 0, hsep, 192, nullptr);

    // z|r = sigmoid(conv gi) -> zrbuf  (MF=2, NOCT=3, 8 ocg: 816 blocks)
    convmf_k<3, 2, 9, 16, 512, 24, 2, 0, 0><<<dim3(51, 8, BB), dim3(256), 0, stream>>>(
        giG, wpzr, b_z, b_r, 192, 384, zrbuf, 384, 0, nullptr, 0, nullptr);

    // giG ch0..191 = r*h
    rh_k<<<dim3((BB * HWN * 24 + 255) / 256), dim3(256), 0, stream>>>(zrbuf, hsep, giG);

    // q = tanh(conv gi) -> qbuf  (MF=2, NOCT=2, 6 ocg: 612 blocks)
    convmf_k<2, 2, 9, 16, 512, 12, 3, 0, 0><<<dim3(51, 6, BB), dim3(256), 0, stream>>>(
        giG, wpq, b_q, b_q, 192, 192, qbuf, 192, 0, nullptr, 0, nullptr);

    // giG ch0..191 = (1-z)h + z q
    hnew_k<<<dim3((BB * HWN * 24 + 255) / 256), dim3(256), 0, stream>>>(zrbuf, hsep, qbuf, giG);

    // out = [dh(112); fh(4)] conv of h' -> f32 CF  (MF=2, NOCT=2, 4 ocg)
    convmf_k<2, 2, 9, 6, 512, 8, 0, 2, 0><<<dim3(51, 4, BB), dim3(256), 0, stream>>>(
        giG, wpdh, b_dh, b_fh, 112, 116, nullptr, 0, 0, nullptr, 0, out);
}

// Round 15
// 511.550 us; speedup vs baseline: 1.1525x; 1.1525x over previous
//
#include <hip/hip_runtime.h>
#include <hip/hip_bf16.h>
#include <math.h>

#define BB 2
#define CC 128
#define HH 60
#define WW 108
#define HWN (HH*WW)
#define GR 160                // zeroed guard rows between batches (>= 109 halo + tile tail)
#define RSTR (HWN + GR)       // guarded row stride per batch

typedef __attribute__((ext_vector_type(8))) short s16x8;
typedef __attribute__((ext_vector_type(4))) float f32x4;
typedef __attribute__((ext_vector_type(4))) unsigned int u32x4;

__device__ __forceinline__ unsigned short f2b(float f) {
    union { float f; unsigned int u; } v; v.f = f;
    unsigned int r = (v.u + 0x7FFFu + ((v.u >> 16) & 1u)) >> 16;
    return (unsigned short)r;
}
__device__ __forceinline__ float b2f(unsigned short b) {
    union { unsigned int u; float f; } v; v.u = ((unsigned int)b) << 16;
    return v.f;
}

// async global->LDS, 16B per lane (casts go through uintptr_t: direct
// reinterpret_cast between address spaces is rejected by hipcc)
__device__ __forceinline__ void gload16(const void* g, void* l) {
    auto gp = reinterpret_cast<const __attribute__((address_space(1))) unsigned int*>(
        reinterpret_cast<uintptr_t>(g));
    auto lp = reinterpret_cast<__attribute__((address_space(3))) unsigned int*>(
        reinterpret_cast<uintptr_t>(l));
    __builtin_amdgcn_global_load_lds(gp, lp, 16, 0, 0);
}

__device__ __forceinline__ s16x8 andm(s16x8 a, unsigned m) {
    u32x4 t = __builtin_bit_cast(u32x4, a);
    t &= m;
    return __builtin_bit_cast(s16x8, t);
}

// ---------------------------------------------------------------------------
// Zero guard rows of a guarded channel-last buffer (base = alloc start).
// ---------------------------------------------------------------------------
__global__ void zero_guard_k(unsigned short* __restrict__ p, int C) {
    int idx = blockIdx.x * 256 + threadIdx.x;
    int cw = C / 8;
    int total = (BB + 1) * GR * cw;
    if (idx >= total) return;
    int g  = idx / (GR * cw);
    int rr = idx % (GR * cw);
    int row = g * RSTR + rr / cw;
    int c8  = (rr % cw) * 8;
    s16x8 z = {};
    *(s16x8*)(p + (size_t)row * C + c8) = z;
}

// ---------------------------------------------------------------------------
// fmap [B][128][HW] f32 -> [B][HW][128] f32 (channel-last, for lookup)
// ---------------------------------------------------------------------------
__global__ void f2cl_k(const float* __restrict__ in, float* __restrict__ out) {
    int n = blockIdx.x * 64 + threadIdx.x;
    int b = blockIdx.y;
    if (n >= HWN) return;
    const float* ip = in + (size_t)b * CC * HWN + n;
    float* op = out + ((size_t)b * HWN + n) * CC;
    for (int c0 = 0; c0 < CC; c0 += 4) {
        float4 o;
        o.x = ip[(size_t)(c0 + 0) * HWN];
        o.y = ip[(size_t)(c0 + 1) * HWN];
        o.z = ip[(size_t)(c0 + 2) * HWN];
        o.w = ip[(size_t)(c0 + 3) * HWN];
        *(float4*)(op + c0) = o;
    }
}

// ---------------------------------------------------------------------------
// ft [B][112][HW] f32 -> guarded [*][128] bf16 (pad 112..127 zero); pre-offset
// ---------------------------------------------------------------------------
__global__ void ft2cl_k(const float* __restrict__ ft, unsigned short* __restrict__ out) {
    int n = blockIdx.x * 64 + threadIdx.x;
    int b = blockIdx.y;
    if (n >= HWN) return;
    const float* ip = ft + (size_t)b * 112 * HWN + n;
    unsigned short* op = out + ((size_t)b * RSTR + n) * 128;
    for (int c0 = 0; c0 < 112; c0 += 8) {
        s16x8 o;
        #pragma unroll
        for (int j = 0; j < 8; j++) o[j] = (short)f2b(ip[(size_t)(c0 + j) * HWN]);
        *(s16x8*)(op + c0) = o;
    }
    s16x8 z = {};
    *(s16x8*)(op + 112) = z;
    *(s16x8*)(op + 120) = z;
}

// ---------------------------------------------------------------------------
// 2x2 avg pool on channel-last f32 maps
// ---------------------------------------------------------------------------
__global__ void pool_k(const float* __restrict__ in, float* __restrict__ out,
                       int Hi, int Wi, int Ho, int Wo) {
    int bp = blockIdx.x;
    int b  = bp / (Ho * Wo);
    int p  = bp % (Ho * Wo);
    int yo = p / Wo, xo = p % Wo;
    int c  = threadIdx.x;
    const float* i0 = in + (((size_t)b * Hi + 2 * yo) * Wi + 2 * xo) * CC;
    float v = i0[c] + i0[CC + c] + i0[(size_t)Wi * CC + c] + i0[(size_t)Wi * CC + CC + c];
    out[(((size_t)b * Ho + yo) * Wo + xo) * CC + c] = 0.25f * v;
}

// ---------------------------------------------------------------------------
// Correlation pyramid lookup -> guarded corr_cl [*][416] bf16 (pre-offset)
// ---------------------------------------------------------------------------
__global__ void lookup_k(const float* __restrict__ f0cl, const float* __restrict__ f1cl,
                         const float* __restrict__ f0p1, const float* __restrict__ f0p2,
                         const float* __restrict__ f0p3,
                         const float* __restrict__ f1p1, const float* __restrict__ f1p2,
                         const float* __restrict__ f1p3,
                         const float* __restrict__ flow0, const float* __restrict__ flow1,
                         const float* __restrict__ embt, unsigned short* __restrict__ corr_cl) {
    int bn = blockIdx.x;
    int b  = bn / HWN;
    int n  = bn % HWN;
    int y  = n / WW, x = n % WW;
    int dir = blockIdx.y;
    int tid = threadIdx.x;
    int lane = tid & 63;
    int lvl  = tid >> 6;

    __shared__ __align__(16) float fvec[CC];
    __shared__ float dsh[4][64];

    const float* fsrc = (dir == 0) ? f0cl : f1cl;
    if (tid < 128) fvec[tid] = fsrc[(size_t)bn * CC + tid];

    float e  = embt[b];
    float sc = (dir == 0) ? (1.0f / e) : (1.0f / (1.0f - e));
    const float* fl = (dir == 0) ? flow1 : flow0;
    float fx = fl[((size_t)(b * 2 + 0) * HH + y) * WW + x];
    float fy = fl[((size_t)(b * 2 + 1) * HH + y) * WW + x];
    float inv = 1.0f / (float)(1 << lvl);
    float cx = ((float)x + fx * sc) * inv;
    float cy = ((float)y + fy * sc) * inv;
    float fx0 = floorf(cx), fy0 = floorf(cy);
    float wx = cx - fx0, wy = cy - fy0;
    int ix0 = (int)fx0, iy0 = (int)fy0;

    const float* map;
    if (dir == 0) map = (lvl == 0) ? f1cl : (lvl == 1) ? f1p1 : (lvl == 2) ? f1p2 : f1p3;
    else          map = (lvl == 0) ? f0cl : (lvl == 1) ? f0p1 : (lvl == 2) ? f0p2 : f0p3;
    int Hl = (lvl == 0) ? 60 : (lvl == 1) ? 30 : (lvl == 2) ? 15 : 7;
    int Wl = (lvl == 0) ? 108 : (lvl == 1) ? 54 : (lvl == 2) ? 27 : 13;

    int g   = lane >> 3;
    int sub = lane & 7;

    __syncthreads();

    const float4* fv4 = (const float4*)fvec;
    #pragma unroll
    for (int p = 0; p < 8; p++) {
        int c  = p * 8 + g;
        int xi = ix0 - 3 + g;
        int yi = iy0 - 3 + p;
        float part = 0.0f;
        if ((unsigned)xi < (unsigned)Wl && (unsigned)yi < (unsigned)Hl) {
            const float4* cp = (const float4*)(map + (((size_t)b * Hl + yi) * Wl + xi) * CC);
            #pragma unroll
            for (int it = 0; it < 4; it++) {
                float4 a = cp[it * 8 + sub];
                float4 f = fv4[it * 8 + sub];
                part += a.x * f.x + a.y * f.y + a.z * f.z + a.w * f.w;
            }
        }
        part += __shfl_xor(part, 1);
        part += __shfl_xor(part, 2);
        part += __shfl_xor(part, 4);
        if (sub == 0) dsh[lvl][c] = part * 0.08838834764831845f;  // 1/sqrt(128)
    }
    __syncthreads();

    if (lane < 49) {
        int r0 = lane / 7, c0 = lane % 7;
        float d00 = dsh[lvl][r0 * 8 + c0],       d01 = dsh[lvl][r0 * 8 + c0 + 1];
        float d10 = dsh[lvl][(r0 + 1) * 8 + c0], d11 = dsh[lvl][(r0 + 1) * 8 + c0 + 1];
        float val = d00 * (1.0f - wx) * (1.0f - wy) + d01 * wx * (1.0f - wy)
                  + d10 * (1.0f - wx) * wy          + d11 * wx * wy;
        int ch = dir * 196 + lvl * 49 + lane;
        corr_cl[((size_t)b * RSTR + n) * 416 + ch] = f2b(val);
    }
}

// ---------------------------------------------------------------------------
// Pack conv weights into LDS-stageable fragment-linear blocks:
// chunk = (((tap*CINW + kb)*NNT + nt)*NB + bi)*64 + lane, 8 bf16/chunk,
// bi = ks32*(NB/2) + ocf;  oc = nt*NTILE + ocf*16 + (lane&15);
// ic = kb*64 + ks32*32 + (lane>>4)*8 + j.
// ---------------------------------------------------------------------------
__global__ void packw2_k(const float* __restrict__ w1, const float* __restrict__ w2,
                         int OC1, int OCreal, int Cin, int TAPS, int CINW, int NNT,
                         int NB, int NTILE, unsigned short* __restrict__ out) {
    int idx = blockIdx.x * 256 + threadIdx.x;
    int total = TAPS * CINW * NNT * NB * 64;
    if (idx >= total) return;
    int lane = idx & 63;
    int rest = idx >> 6;
    int bi = rest % NB; rest /= NB;
    int nt = rest % NNT; rest /= NNT;
    int kb = rest % CINW;
    int tap = rest / CINW;
    int ks32 = bi / (NB / 2);
    int ocf  = bi % (NB / 2);
    int oc = nt * NTILE + ocf * 16 + (lane & 15);
    int kbase = kb * 64 + ks32 * 32 + (lane >> 4) * 8;
    s16x8 o;
    #pragma unroll
    for (int j = 0; j < 8; j++) {
        int ic = kbase + j;
        float val = 0.0f;
        if (oc < OCreal && ic < Cin) {
            val = (oc < OC1) ? w1[((size_t)oc * Cin + ic) * TAPS + tap]
                             : w2[((size_t)(oc - OC1) * Cin + ic) * TAPS + tap];
        }
        o[j] = (short)f2b(val);
    }
    *(s16x8*)(out + (size_t)idx * 8) = o;
}

// ---------------------------------------------------------------------------
// m97-style LDS-staged implicit-GEMM conv.
// Tile: M = 2*WM*16 pixels, N = 2*WN*16 oc. 4 waves (2M x 2N).
// Per K-step (tap, kb=64ch): stage A,B fragment-linear via global_load_lds,
// vmcnt(0)+barrier, 2x(WM+WN) ds_read_b128 + 2*WM*WN MFMA, barrier.
// Halo via zero-guard rows; x-wrap via post-read AND mask (dx!=0 taps only).
// ACT: 0 none 1 relu 2 sigmoid 3 tanh. EPI: 0 bf16 CL, 1 bf16 CL x2, 2 f32 CF.
// ---------------------------------------------------------------------------
template<int WM, int WN, int TAPS, int CINW, int NCS, int NNT, int ACT, int EPI, int OGUARD>
__launch_bounds__(256)
__global__ void convg_k(const unsigned short* __restrict__ gin,
                        const unsigned short* __restrict__ wp,
                        const float* __restrict__ bias1, const float* __restrict__ bias2,
                        int OC1, int OCreal,
                        unsigned short* __restrict__ gout, int OCS, int ocoff,
                        unsigned short* __restrict__ gout2, int OCS2,
                        float* __restrict__ fout) {
    constexpr int MTILE  = 2 * WM * 16;
    constexpr int NTILE  = 2 * WN * 16;
    constexpr int ABYTES = WM * 4096;     // 2 ks32 * 2WM blocks * 1KB
    constexpr int BBYTES = WN * 4096;
    __shared__ __align__(16) char smem[ABYTES + BBYTES];

    int tid  = threadIdx.x;
    int lane = tid & 63;
    int w    = tid >> 6;
    int wm = w & 1, wn = w >> 1;
    int p0 = blockIdx.x * MTILE;
    int nt = blockIdx.y;
    int b  = blockIdx.z;

    const int rowB = NCS * 2;                      // bytes per input row
    const char* ginB = (const char*)gin + (size_t)(b * RSTR + p0) * rowB;

    // per-lane invariant A source offset: row(lane&15) within a 16-row block + ch-group
    int vsrcA = (lane & 15) * rowB + (lane >> 4) * 16;

    // x-edge keep masks per local M-frag
    unsigned kmL[WM], kmR[WM];
    #pragma unroll
    for (int fi = 0; fi < WM; fi++) {
        int p = p0 + (wm * WM + fi) * 16 + (lane & 15);
        int px = p % WW;
        kmL[fi] = (px >= 1) ? 0xFFFFFFFFu : 0u;
        kmR[fi] = (px <= WW - 2) ? 0xFFFFFFFFu : 0u;
    }

    f32x4 acc[WM][WN];
    #pragma unroll
    for (int fi = 0; fi < WM; fi++)
        #pragma unroll
        for (int j = 0; j < WN; j++) acc[fi][j] = f32x4{0.f, 0.f, 0.f, 0.f};

    char* aB = smem + lane * 16;                    // A ds_read base
    char* bB = smem + ABYTES + lane * 16;           // B ds_read base
    const char* wbase = (const char*)wp;

    for (int tap = 0; tap < TAPS; tap++) {
        const int dy = (TAPS == 1) ? 0 : (tap / 3 - 1);
        const int dx = (TAPS == 1) ? 0 : (tap % 3 - 1);
        const char* gtap = ginB + (ptrdiff_t)(dy * WW + dx) * rowB;
        unsigned kma[WM];
        #pragma unroll
        for (int fi = 0; fi < WM; fi++)
            kma[fi] = (dx == 0) ? 0xFFFFFFFFu : ((dx < 0) ? kmL[fi] : kmR[fi]);
        const bool doMask = (dx != 0);

        #pragma unroll
        for (int kb = 0; kb < CINW; kb++) {
            // ---- stage A: WM issues/wave, block bi = w*WM+i -> (ks32, mfg) ----
            #pragma unroll
            for (int i = 0; i < WM; i++) {
                int bi   = w * WM + i;
                int ks32 = bi / (2 * WM);
                int mfg  = bi % (2 * WM);
                const char* src = gtap + (ptrdiff_t)(mfg * 16) * rowB
                                + (kb * 64 + ks32 * 32) * 2 + vsrcA;
                gload16(src, smem + bi * 1024);
            }
            // ---- stage B: WN issues/wave, linear copy of packed block ----
            const char* wsrc = wbase + ((size_t)((tap * CINW + kb) * NNT + nt)) * (4 * WN * 1024);
            #pragma unroll
            for (int j = 0; j < WN; j++) {
                int bi = w * WN + j;
                gload16(wsrc + bi * 1024 + lane * 16, smem + ABYTES + bi * 1024);
            }
            asm volatile("s_waitcnt vmcnt(0)" ::: "memory");
            __syncthreads();
            // ---- compute: 2 ks32 x (WM A-reads + WN B-reads + WM*WN MFMA) ----
            #pragma unroll
            for (int ks = 0; ks < 2; ks++) {
                s16x8 af[WM], bf[WN];
                #pragma unroll
                for (int fi = 0; fi < WM; fi++) {
                    af[fi] = *(const s16x8*)(aB + (ks * 2 * WM + wm * WM + fi) * 1024);
                    if (doMask) af[fi] = andm(af[fi], kma[fi]);
                }
                #pragma unroll
                for (int j = 0; j < WN; j++)
                    bf[j] = *(const s16x8*)(bB + (ks * 2 * WN + wn * WN + j) * 1024);
                #pragma unroll
                for (int fi = 0; fi < WM; fi++)
                    #pragma unroll
                    for (int j = 0; j < WN; j++)
                        acc[fi][j] = __builtin_amdgcn_mfma_f32_16x16x32_bf16(
                            af[fi], bf[j], acc[fi][j], 0, 0, 0);
            }
            __syncthreads();
        }
    }

    // ---- epilogue ----
    int oc_l = lane & 15;
    #pragma unroll
    for (int j = 0; j < WN; j++) {
        int oc = nt * NTILE + (wn * WN + j) * 16 + oc_l;
        float bs = 0.0f;
        if (oc < OCreal) bs = (oc < OC1) ? bias1[oc] : bias2[oc - OC1];
        #pragma unroll
        for (int fi = 0; fi < WM; fi++) {
            int prow = p0 + (wm * WM + fi) * 16 + (lane >> 4) * 4;
            #pragma unroll
            for (int r = 0; r < 4; r++) {
                int p = prow + r;
                if (p >= HWN) continue;
                float vv = acc[fi][j][r] + bs;
                if (ACT == 1) vv = fmaxf(vv, 0.0f);
                else if (ACT == 2) vv = 1.0f / (1.0f + __expf(-vv));
                else if (ACT == 3) vv = tanhf(vv);
                if (EPI == 2) {
                    if (oc < OCreal) fout[((size_t)b * OCreal + oc) * HWN + p] = vv;
                } else {
                    unsigned short bvv = f2b(vv);
                    size_t row = (size_t)b * (OGUARD ? RSTR : HWN) + p;
                    gout[row * OCS + ocoff + oc] = bvv;
                    if (EPI == 1) gout2[((size_t)b * HWN + p) * OCS2 + oc] = bvv;
                }
            }
        }
    }
}

// ---------------------------------------------------------------------------
// flow conv (4->64, 3x3, relu), direct f32, writes guarded gi ch 448..511
// ---------------------------------------------------------------------------
__global__ void flowconv_k(const float* __restrict__ flow0, const float* __restrict__ flow1,
                           const float* __restrict__ w, const float* __restrict__ bias,
                           unsigned short* __restrict__ gi) {
    int n = blockIdx.x * 64 + threadIdx.x;
    int b = blockIdx.y;
    if (n >= HWN) return;
    int y = n / WW, x = n - y * WW;
    float v[36];
    for (int c = 0; c < 4; c++) {
        const float* pl = (c < 2) ? flow0 + ((size_t)b * 2 + c) * HWN
                                  : flow1 + ((size_t)b * 2 + (c - 2)) * HWN;
        #pragma unroll
        for (int dy = -1; dy <= 1; dy++)
            #pragma unroll
            for (int dx = -1; dx <= 1; dx++) {
                int yy = y + dy, xx = x + dx;
                v[c * 9 + (dy + 1) * 3 + (dx + 1)] =
                    (((unsigned)yy < (unsigned)HH) && ((unsigned)xx < (unsigned)WW))
                        ? pl[(size_t)yy * WW + xx] : 0.0f;
            }
    }
    unsigned short* op = gi + ((size_t)b * RSTR + n) * 512 + 448;
    for (int oc0 = 0; oc0 < 64; oc0 += 8) {
        s16x8 o;
        #pragma unroll
        for (int j = 0; j < 8; j++) {
            int oc = oc0 + j;
            const float* wpp = w + (size_t)oc * 36;
            float a = bias[oc];
            #pragma unroll
            for (int k = 0; k < 36; k++) a += wpp[k] * v[k];
            o[j] = (short)f2b(fmaxf(a, 0.0f));
        }
        *(s16x8*)(op + oc0) = o;
    }
}

// ---------------------------------------------------------------------------
// rh: guarded gi[ch 0..191] = r * h
// ---------------------------------------------------------------------------
__global__ void rh_k(const unsigned short* __restrict__ zr, const unsigned short* __restrict__ hs,
                     unsigned short* __restrict__ gi) {
    int idx = blockIdx.x * 256 + threadIdx.x;
    if (idx >= BB * HWN * 24) return;
    int n = idx / 24, c8 = (idx % 24) * 8;
    int b = n / HWN, nn = n - b * HWN;
    s16x8 r = *(const s16x8*)(zr + (size_t)n * 384 + 192 + c8);
    s16x8 h = *(const s16x8*)(hs + (size_t)n * 192 + c8);
    s16x8 o;
    #pragma unroll
    for (int j = 0; j < 8; j++)
        o[j] = (short)f2b(b2f((unsigned short)r[j]) * b2f((unsigned short)h[j]));
    *(s16x8*)(gi + ((size_t)b * RSTR + nn) * 512 + c8) = o;
}

// ---------------------------------------------------------------------------
// hnew: guarded gi[ch 0..191] = (1-z)*h + z*q
// ---------------------------------------------------------------------------
__global__ void hnew_k(const unsigned short* __restrict__ zr, const unsigned short* __restrict__ hs,
                       const unsigned short* __restrict__ q, unsigned short* __restrict__ gi) {
    int idx = blockIdx.x * 256 + threadIdx.x;
    if (idx >= BB * HWN * 24) return;
    int n = idx / 24, c8 = (idx % 24) * 8;
    int b = n / HWN, nn = n - b * HWN;
    s16x8 z = *(const s16x8*)(zr + (size_t)n * 384 + c8);
    s16x8 h = *(const s16x8*)(hs + (size_t)n * 192 + c8);
    s16x8 qq = *(const s16x8*)(q + (size_t)n * 192 + c8);
    s16x8 o;
    #pragma unroll
    for (int j = 0; j < 8; j++) {
        float zf = b2f((unsigned short)z[j]);
        o[j] = (short)f2b((1.0f - zf) * b2f((unsigned short)h[j]) + zf * b2f((unsigned short)qq[j]));
    }
    *(s16x8*)(gi + ((size_t)b * RSTR + nn) * 512 + c8) = o;
}

// ---------------------------------------------------------------------------
extern "C" void kernel_launch(void* const* d_in, const int* in_sizes, int n_in,
                              void* d_out, int out_size, void* d_ws, size_t ws_size,
                              hipStream_t stream) {
    const float* fmap0 = (const float*)d_in[0];
    const float* fmap1 = (const float*)d_in[1];
    const float* ft    = (const float*)d_in[2];
    const float* flow0 = (const float*)d_in[3];
    const float* flow1 = (const float*)d_in[4];
    const float* embt  = (const float*)d_in[5];
    const float* w_corr = (const float*)d_in[6];
    const float* b_corr = (const float*)d_in[7];
    const float* w_flow = (const float*)d_in[8];
    const float* b_flow = (const float*)d_in[9];
    const float* w_ctx  = (const float*)d_in[10];
    const float* b_ctx  = (const float*)d_in[11];
    const float* w_z    = (const float*)d_in[12];
    const float* b_z    = (const float*)d_in[13];
    const float* w_r    = (const float*)d_in[14];
    const float* b_r    = (const float*)d_in[15];
    const float* w_q    = (const float*)d_in[16];
    const float* b_q    = (const float*)d_in[17];
    const float* w_fh   = (const float*)d_in[18];
    const float* b_fh   = (const float*)d_in[19];
    const float* w_dh   = (const float*)d_in[20];
    const float* b_dh   = (const float*)d_in[21];
    float* out = (float*)d_out;

    char* ws = (char*)d_ws;
    size_t off = 0;
    auto alloc = [&](size_t bytes) { size_t o = off; off += (bytes + 255) & ~(size_t)255; return o; };

    const size_t GROWS = (size_t)GR + (size_t)BB * RSTR;

    float* f0cl = (float*)(ws + alloc((size_t)BB * HWN * CC * 4));
    float* f1cl = (float*)(ws + alloc((size_t)BB * HWN * CC * 4));
    float* f0p1 = (float*)(ws + alloc((size_t)BB * 30 * 54 * CC * 4));
    float* f0p2 = (float*)(ws + alloc((size_t)BB * 15 * 27 * CC * 4));
    float* f0p3 = (float*)(ws + alloc((size_t)BB * 7 * 13 * CC * 4));
    float* f1p1 = (float*)(ws + alloc((size_t)BB * 30 * 54 * CC * 4));
    float* f1p2 = (float*)(ws + alloc((size_t)BB * 15 * 27 * CC * 4));
    float* f1p3 = (float*)(ws + alloc((size_t)BB * 7 * 13 * CC * 4));
    unsigned short* ftcl   = (unsigned short*)(ws + alloc(GROWS * 128 * 2));
    unsigned short* corrcl = (unsigned short*)(ws + alloc(GROWS * 416 * 2));
    unsigned short* gi     = (unsigned short*)(ws + alloc(GROWS * 512 * 2));
    unsigned short* hsep   = (unsigned short*)(ws + alloc((size_t)BB * HWN * 192 * 2));
    unsigned short* zrbuf  = (unsigned short*)(ws + alloc((size_t)BB * HWN * 384 * 2));
    unsigned short* qbuf   = (unsigned short*)(ws + alloc((size_t)BB * HWN * 192 * 2));
    // packed weights (fragment-linear blocks), chunk counts x 16B
    unsigned short* wpzr   = (unsigned short*)(ws + alloc((size_t)9 * 8 * 3 * 16 * 64 * 16));
    unsigned short* wpq    = (unsigned short*)(ws + alloc((size_t)9 * 8 * 2 * 12 * 64 * 16));
    unsigned short* wpctx  = (unsigned short*)(ws + alloc((size_t)9 * 2 * 2 * 12 * 64 * 16));
    unsigned short* wpdh   = (unsigned short*)(ws + alloc((size_t)9 * 3 * 1 * 16 * 64 * 16));
    unsigned short* wpcorr = (unsigned short*)(ws + alloc((size_t)1 * 7 * 2 * 16 * 64 * 16));

    unsigned short* ftclG   = ftcl   + (size_t)GR * 128;
    unsigned short* corrclG = corrcl + (size_t)GR * 416;
    unsigned short* giG     = gi     + (size_t)GR * 512;

    // zero guard rows
    zero_guard_k<<<dim3(((BB + 1) * GR * (512 / 8) + 255) / 256), dim3(256), 0, stream>>>(gi, 512);
    zero_guard_k<<<dim3(((BB + 1) * GR * (128 / 8) + 255) / 256), dim3(256), 0, stream>>>(ftcl, 128);
    zero_guard_k<<<dim3(((BB + 1) * GR * (416 / 8) + 255) / 256), dim3(256), 0, stream>>>(corrcl, 416);

    // weight packing (fragment-linear)
    packw2_k<<<dim3((9 * 8 * 3 * 16 * 64 + 255) / 256), dim3(256), 0, stream>>>(
        w_z, w_r, 192, 384, 512, 9, 8, 3, 16, 128, wpzr);
    packw2_k<<<dim3((9 * 8 * 2 * 12 * 64 + 255) / 256), dim3(256), 0, stream>>>(
        w_q, w_q, 192, 192, 512, 9, 8, 2, 12, 96, wpq);
    packw2_k<<<dim3((9 * 2 * 2 * 12 * 64 + 255) / 256), dim3(256), 0, stream>>>(
        w_ctx, w_ctx, 192, 192, 112, 9, 2, 2, 12, 96, wpctx);
    packw2_k<<<dim3((9 * 3 * 1 * 16 * 64 + 255) / 256), dim3(256), 0, stream>>>(
        w_dh, w_fh, 112, 116, 192, 9, 3, 1, 16, 128, wpdh);
    packw2_k<<<dim3((1 * 7 * 2 * 16 * 64 + 255) / 256), dim3(256), 0, stream>>>(
        w_corr, w_corr, 256, 256, 392, 1, 7, 2, 16, 128, wpcorr);

    // channel-last transposes + pyramids
    f2cl_k<<<dim3((HWN + 63) / 64, BB), dim3(64), 0, stream>>>(fmap0, f0cl);
    f2cl_k<<<dim3((HWN + 63) / 64, BB), dim3(64), 0, stream>>>(fmap1, f1cl);
    ft2cl_k<<<dim3((HWN + 63) / 64, BB), dim3(64), 0, stream>>>(ft, ftclG);
    pool_k<<<dim3(BB * 30 * 54), dim3(128), 0, stream>>>(f0cl, f0p1, 60, 108, 30, 54);
    pool_k<<<dim3(BB * 15 * 27), dim3(128), 0, stream>>>(f0p1, f0p2, 30, 54, 15, 27);
    pool_k<<<dim3(BB * 7 * 13),  dim3(128), 0, stream>>>(f0p2, f0p3, 15, 27, 7, 13);
    pool_k<<<dim3(BB * 30 * 54), dim3(128), 0, stream>>>(f1cl, f1p1, 60, 108, 30, 54);
    pool_k<<<dim3(BB * 15 * 27), dim3(128), 0, stream>>>(f1p1, f1p2, 30, 54, 15, 27);
    pool_k<<<dim3(BB * 7 * 13),  dim3(128), 0, stream>>>(f1p2, f1p3, 15, 27, 7, 13);

    // lookup -> guarded corr_cl bf16
    lookup_k<<<dim3(BB * HWN, 2), dim3(256), 0, stream>>>(
        f0cl, f1cl, f0p1, f0p2, f0p3, f1p1, f1p2, f1p3,
        flow0, flow1, embt, corrclG);

    // ffeat -> giG ch 448..511
    flowconv_k<<<dim3((HWN + 63) / 64, BB), dim3(64), 0, stream>>>(flow0, flow1, w_flow, b_flow, giG);

    // cfeat = relu(1x1 conv corrcl) -> giG ch 192..447   (128x128 tile, NNT=2)
    convg_k<4, 4, 1, 7, 416, 2, 1, 0, 1><<<dim3(51, 2, BB), dim3(256), 0, stream>>>(
        corrclG, wpcorr, b_corr, b_corr, 256, 256, giG, 512, 192, nullptr, 0, nullptr);

    // h = tanh(ctx conv ftcl) -> giG ch 0..191 AND hsep  (128x96 tile, NNT=2)
    convg_k<4, 3, 9, 2, 128, 2, 3, 1, 1><<<dim3(51, 2, BB), dim3(256), 0, stream>>>(
        ftclG, wpctx, b_ctx, b_ctx, 192, 192, giG, 512, 0, hsep, 192, nullptr);

    // z|r = sigmoid(conv gi) -> zrbuf [B][HW][384]       (128x128 tile, NNT=3)
    convg_k<4, 4, 9, 8, 512, 3, 2, 0, 0><<<dim3(51, 3, BB), dim3(256), 0, stream>>>(
        giG, wpzr, b_z, b_r, 192, 384, zrbuf, 384, 0, nullptr, 0, nullptr);

    // giG ch0..191 = r*h
    rh_k<<<dim3((BB * HWN * 24 + 255) / 256), dim3(256), 0, stream>>>(zrbuf, hsep, giG);

    // q = tanh(conv gi) -> qbuf                          (128x96 tile, NNT=2)
    convg_k<4, 3, 9, 8, 512, 2, 3, 0, 0><<<dim3(51, 2, BB), dim3(256), 0, stream>>>(
        giG, wpq, b_q, b_q, 192, 192, qbuf, 192, 0, nullptr, 0, nullptr);

    // giG ch0..191 = (1-z)h + z q
    hnew_k<<<dim3((BB * HWN * 24 + 255) / 256), dim3(256), 0, stream>>>(zrbuf, hsep, qbuf, giG);

    // out = [dh(112); fh(4)] conv of h' -> f32 CF        (64x128 tile, NNT=1)
    convg_k<2, 4, 9, 3, 512, 1, 0, 2, 0><<<dim3(102, 1, BB), dim3(256), 0, stream>>>(
        giG, wpdh, b_dh, b_fh, 112, 116, nullptr, 0, 0, nullptr, 0, out);
}

// Round 16
// 407.543 us; speedup vs baseline: 1.4466x; 1.2552x over previous
//
#include <hip/hip_runtime.h>
#include <hip/hip_bf16.h>
#include <math.h>

#define BB 2
#define CC 128
#define HH 60
#define WW 108
#define HWN (HH*WW)
#define GR 160                // zeroed guard rows between batches (>= 109 halo + tile tail)
#define RSTR (HWN + GR)       // guarded row stride per batch

typedef __attribute__((ext_vector_type(8))) short s16x8;
typedef __attribute__((ext_vector_type(4))) float f32x4;
typedef __attribute__((ext_vector_type(4))) unsigned int u32x4;

__device__ __forceinline__ unsigned short f2b(float f) {
    union { float f; unsigned int u; } v; v.f = f;
    unsigned int r = (v.u + 0x7FFFu + ((v.u >> 16) & 1u)) >> 16;
    return (unsigned short)r;
}
__device__ __forceinline__ float b2f(unsigned short b) {
    union { unsigned int u; float f; } v; v.u = ((unsigned int)b) << 16;
    return v.f;
}

// async global->LDS, 16B per lane (casts go through uintptr_t)
__device__ __forceinline__ void gload16(const void* g, void* l) {
    auto gp = reinterpret_cast<const __attribute__((address_space(1))) unsigned int*>(
        reinterpret_cast<uintptr_t>(g));
    auto lp = reinterpret_cast<__attribute__((address_space(3))) unsigned int*>(
        reinterpret_cast<uintptr_t>(l));
    __builtin_amdgcn_global_load_lds(gp, lp, 16, 0, 0);
}

__device__ __forceinline__ s16x8 andm(s16x8 a, unsigned m) {
    u32x4 t = __builtin_bit_cast(u32x4, a);
    t &= m;
    return __builtin_bit_cast(s16x8, t);
}

// ---------------------------------------------------------------------------
// Zero guard rows of a guarded channel-last buffer (base = alloc start).
// ---------------------------------------------------------------------------
__global__ void zero_guard_k(unsigned short* __restrict__ p, int C) {
    int idx = blockIdx.x * 256 + threadIdx.x;
    int cw = C / 8;
    int total = (BB + 1) * GR * cw;
    if (idx >= total) return;
    int g  = idx / (GR * cw);
    int rr = idx % (GR * cw);
    int row = g * RSTR + rr / cw;
    int c8  = (rr % cw) * 8;
    s16x8 z = {};
    *(s16x8*)(p + (size_t)row * C + c8) = z;
}

// ---------------------------------------------------------------------------
// fmap [B][128][HW] f32 -> [B][HW][128] f32 (channel-last, for lookup)
// ---------------------------------------------------------------------------
__global__ void f2cl_k(const float* __restrict__ in, float* __restrict__ out) {
    int n = blockIdx.x * 64 + threadIdx.x;
    int b = blockIdx.y;
    if (n >= HWN) return;
    const float* ip = in + (size_t)b * CC * HWN + n;
    float* op = out + ((size_t)b * HWN + n) * CC;
    for (int c0 = 0; c0 < CC; c0 += 4) {
        float4 o;
        o.x = ip[(size_t)(c0 + 0) * HWN];
        o.y = ip[(size_t)(c0 + 1) * HWN];
        o.z = ip[(size_t)(c0 + 2) * HWN];
        o.w = ip[(size_t)(c0 + 3) * HWN];
        *(float4*)(op + c0) = o;
    }
}

// ---------------------------------------------------------------------------
// ft [B][112][HW] f32 -> guarded [*][128] bf16 (pad 112..127 zero); pre-offset
// ---------------------------------------------------------------------------
__global__ void ft2cl_k(const float* __restrict__ ft, unsigned short* __restrict__ out) {
    int n = blockIdx.x * 64 + threadIdx.x;
    int b = blockIdx.y;
    if (n >= HWN) return;
    const float* ip = ft + (size_t)b * 112 * HWN + n;
    unsigned short* op = out + ((size_t)b * RSTR + n) * 128;
    for (int c0 = 0; c0 < 112; c0 += 8) {
        s16x8 o;
        #pragma unroll
        for (int j = 0; j < 8; j++) o[j] = (short)f2b(ip[(size_t)(c0 + j) * HWN]);
        *(s16x8*)(op + c0) = o;
    }
    s16x8 z = {};
    *(s16x8*)(op + 112) = z;
    *(s16x8*)(op + 120) = z;
}

// ---------------------------------------------------------------------------
// 2x2 avg pool on channel-last f32 maps
// ---------------------------------------------------------------------------
__global__ void pool_k(const float* __restrict__ in, float* __restrict__ out,
                       int Hi, int Wi, int Ho, int Wo) {
    int bp = blockIdx.x;
    int b  = bp / (Ho * Wo);
    int p  = bp % (Ho * Wo);
    int yo = p / Wo, xo = p % Wo;
    int c  = threadIdx.x;
    const float* i0 = in + (((size_t)b * Hi + 2 * yo) * Wi + 2 * xo) * CC;
    float v = i0[c] + i0[CC + c] + i0[(size_t)Wi * CC + c] + i0[(size_t)Wi * CC + CC + c];
    out[(((size_t)b * Ho + yo) * Wo + xo) * CC + c] = 0.25f * v;
}

// ---------------------------------------------------------------------------
// Correlation pyramid lookup -> guarded corr_cl [*][416] bf16 (pre-offset)
// ---------------------------------------------------------------------------
__global__ void lookup_k(const float* __restrict__ f0cl, const float* __restrict__ f1cl,
                         const float* __restrict__ f0p1, const float* __restrict__ f0p2,
                         const float* __restrict__ f0p3,
                         const float* __restrict__ f1p1, const float* __restrict__ f1p2,
                         const float* __restrict__ f1p3,
                         const float* __restrict__ flow0, const float* __restrict__ flow1,
                         const float* __restrict__ embt, unsigned short* __restrict__ corr_cl) {
    int bn = blockIdx.x;
    int b  = bn / HWN;
    int n  = bn % HWN;
    int y  = n / WW, x = n % WW;
    int dir = blockIdx.y;
    int tid = threadIdx.x;
    int lane = tid & 63;
    int lvl  = tid >> 6;

    __shared__ __align__(16) float fvec[CC];
    __shared__ float dsh[4][64];

    const float* fsrc = (dir == 0) ? f0cl : f1cl;
    if (tid < 128) fvec[tid] = fsrc[(size_t)bn * CC + tid];

    float e  = embt[b];
    float sc = (dir == 0) ? (1.0f / e) : (1.0f / (1.0f - e));
    const float* fl = (dir == 0) ? flow1 : flow0;
    float fx = fl[((size_t)(b * 2 + 0) * HH + y) * WW + x];
    float fy = fl[((size_t)(b * 2 + 1) * HH + y) * WW + x];
    float inv = 1.0f / (float)(1 << lvl);
    float cx = ((float)x + fx * sc) * inv;
    float cy = ((float)y + fy * sc) * inv;
    float fx0 = floorf(cx), fy0 = floorf(cy);
    float wx = cx - fx0, wy = cy - fy0;
    int ix0 = (int)fx0, iy0 = (int)fy0;

    const float* map;
    if (dir == 0) map = (lvl == 0) ? f1cl : (lvl == 1) ? f1p1 : (lvl == 2) ? f1p2 : f1p3;
    else          map = (lvl == 0) ? f0cl : (lvl == 1) ? f0p1 : (lvl == 2) ? f0p2 : f0p3;
    int Hl = (lvl == 0) ? 60 : (lvl == 1) ? 30 : (lvl == 2) ? 15 : 7;
    int Wl = (lvl == 0) ? 108 : (lvl == 1) ? 54 : (lvl == 2) ? 27 : 13;

    int g   = lane >> 3;
    int sub = lane & 7;

    __syncthreads();

    const float4* fv4 = (const float4*)fvec;
    #pragma unroll
    for (int p = 0; p < 8; p++) {
        int c  = p * 8 + g;
        int xi = ix0 - 3 + g;
        int yi = iy0 - 3 + p;
        float part = 0.0f;
        if ((unsigned)xi < (unsigned)Wl && (unsigned)yi < (unsigned)Hl) {
            const float4* cp = (const float4*)(map + (((size_t)b * Hl + yi) * Wl + xi) * CC);
            #pragma unroll
            for (int it = 0; it < 4; it++) {
                float4 a = cp[it * 8 + sub];
                float4 f = fv4[it * 8 + sub];
                part += a.x * f.x + a.y * f.y + a.z * f.z + a.w * f.w;
            }
        }
        part += __shfl_xor(part, 1);
        part += __shfl_xor(part, 2);
        part += __shfl_xor(part, 4);
        if (sub == 0) dsh[lvl][c] = part * 0.08838834764831845f;  // 1/sqrt(128)
    }
    __syncthreads();

    if (lane < 49) {
        int r0 = lane / 7, c0 = lane % 7;
        float d00 = dsh[lvl][r0 * 8 + c0],       d01 = dsh[lvl][r0 * 8 + c0 + 1];
        float d10 = dsh[lvl][(r0 + 1) * 8 + c0], d11 = dsh[lvl][(r0 + 1) * 8 + c0 + 1];
        float val = d00 * (1.0f - wx) * (1.0f - wy) + d01 * wx * (1.0f - wy)
                  + d10 * (1.0f - wx) * wy          + d11 * wx * wy;
        int ch = dir * 196 + lvl * 49 + lane;
        corr_cl[((size_t)b * RSTR + n) * 416 + ch] = f2b(val);
    }
}

// ---------------------------------------------------------------------------
// Pack conv weights into LDS-stageable fragment-linear blocks:
// chunk = (((tap*CINW + kb)*NNT + nt)*NB + bi)*64 + lane, 8 bf16/chunk,
// bi = ks32*(NB/2) + ocf;  oc = nt*NTILE + ocf*16 + (lane&15);
// ic = kb*64 + ks32*32 + (lane>>4)*8 + j.
// ---------------------------------------------------------------------------
__global__ void packw2_k(const float* __restrict__ w1, const float* __restrict__ w2,
                         int OC1, int OCreal, int Cin, int TAPS, int CINW, int NNT,
                         int NB, int NTILE, unsigned short* __restrict__ out) {
    int idx = blockIdx.x * 256 + threadIdx.x;
    int total = TAPS * CINW * NNT * NB * 64;
    if (idx >= total) return;
    int lane = idx & 63;
    int rest = idx >> 6;
    int bi = rest % NB; rest /= NB;
    int nt = rest % NNT; rest /= NNT;
    int kb = rest % CINW;
    int tap = rest / CINW;
    int ks32 = bi / (NB / 2);
    int ocf  = bi % (NB / 2);
    int oc = nt * NTILE + ocf * 16 + (lane & 15);
    int kbase = kb * 64 + ks32 * 32 + (lane >> 4) * 8;
    s16x8 o;
    #pragma unroll
    for (int j = 0; j < 8; j++) {
        int ic = kbase + j;
        float val = 0.0f;
        if (oc < OCreal && ic < Cin) {
            val = (oc < OC1) ? w1[((size_t)oc * Cin + ic) * TAPS + tap]
                             : w2[((size_t)(oc - OC1) * Cin + ic) * TAPS + tap];
        }
        o[j] = (short)f2b(val);
    }
    *(s16x8*)(out + (size_t)idx * 8) = o;
}

// ---------------------------------------------------------------------------
// Double-buffered LDS-staged implicit-GEMM conv (issue-early pipeline).
// Tile: M = 2*WM*16 pixels, N = 2*WN*16 oc. 4 waves (2M x 2N).
// Per K-step s: issue stage(s+1) into half cur^1, compute from half cur,
// __syncthreads (drain is cheap: loads had the compute phase in flight),
// swap. Halo via zero-guard rows; x-wrap via post-read AND mask.
// ACT: 0 none 1 relu 2 sigmoid 3 tanh. EPI: 0 bf16 CL, 1 bf16 CL x2, 2 f32 CF.
// ---------------------------------------------------------------------------
template<int WM, int WN, int TAPS, int CINW, int NCS, int NNT, int ACT, int EPI, int OGUARD>
__launch_bounds__(256)
__global__ void convg_k(const unsigned short* __restrict__ gin,
                        const unsigned short* __restrict__ wp,
                        const float* __restrict__ bias1, const float* __restrict__ bias2,
                        int OC1, int OCreal,
                        unsigned short* __restrict__ gout, int OCS, int ocoff,
                        unsigned short* __restrict__ gout2, int OCS2,
                        float* __restrict__ fout) {
    constexpr int MTILE  = 2 * WM * 16;
    constexpr int NTILE  = 2 * WN * 16;
    constexpr int ABYTES = WM * 4096;     // 2 ks32 * 2WM blocks * 1KB
    constexpr int BBYTES = WN * 4096;
    constexpr int HBYTES = ABYTES + BBYTES;
    constexpr int NSTEP  = TAPS * CINW;
    __shared__ __align__(16) char smem[2 * HBYTES];

    int tid  = threadIdx.x;
    int lane = tid & 63;
    int w    = tid >> 6;
    int wm = w & 1, wn = w >> 1;
    int p0 = blockIdx.x * MTILE;
    int nt = blockIdx.y;
    int b  = blockIdx.z;

    const int rowB = NCS * 2;                      // bytes per input row
    const char* ginB = (const char*)gin + (size_t)(b * RSTR + p0) * rowB;

    // per-lane invariant A source offset
    int vsrcA = (lane & 15) * rowB + (lane >> 4) * 16;

    // x-edge keep masks per local M-frag
    unsigned kmL[WM], kmR[WM];
    #pragma unroll
    for (int fi = 0; fi < WM; fi++) {
        int p = p0 + (wm * WM + fi) * 16 + (lane & 15);
        int px = p % WW;
        kmL[fi] = (px >= 1) ? 0xFFFFFFFFu : 0u;
        kmR[fi] = (px <= WW - 2) ? 0xFFFFFFFFu : 0u;
    }

    f32x4 acc[WM][WN];
    #pragma unroll
    for (int fi = 0; fi < WM; fi++)
        #pragma unroll
        for (int j = 0; j < WN; j++) acc[fi][j] = f32x4{0.f, 0.f, 0.f, 0.f};

    const char* wbase = (const char*)wp;

    auto stageStep = [&](int s, int half) {
        int tap = (TAPS == 1) ? 0 : (s / CINW);
        int kb  = s - tap * CINW;
        int dy  = (TAPS == 1) ? 0 : (tap / 3 - 1);
        int dx  = (TAPS == 1) ? 0 : (tap % 3 - 1);
        const char* gtap = ginB + (ptrdiff_t)(dy * WW + dx) * rowB;
        #pragma unroll
        for (int i = 0; i < WM; i++) {
            int bi   = w * WM + i;
            int ks32 = bi / (2 * WM);
            int mfg  = bi % (2 * WM);
            const char* src = gtap + (ptrdiff_t)(mfg * 16) * rowB
                            + (kb * 64 + ks32 * 32) * 2 + vsrcA;
            gload16(src, smem + half * HBYTES + bi * 1024);
        }
        const char* wsrc = wbase + ((size_t)((tap * CINW + kb) * NNT + nt)) * (4 * WN * 1024);
        #pragma unroll
        for (int j = 0; j < WN; j++) {
            int bi = w * WN + j;
            gload16(wsrc + bi * 1024 + lane * 16, smem + half * HBYTES + ABYTES + bi * 1024);
        }
    };

    stageStep(0, 0);
    __syncthreads();

    int cur = 0;
    for (int s = 0; s < NSTEP; s++) {
        if (s + 1 < NSTEP) stageStep(s + 1, cur ^ 1);   // issue-early prefetch
        int tap = (TAPS == 1) ? 0 : (s / CINW);
        int dx  = (TAPS == 1) ? 0 : (tap % 3 - 1);
        const char* aB = smem + cur * HBYTES + lane * 16;
        const char* bB = smem + cur * HBYTES + ABYTES + lane * 16;
        #pragma unroll
        for (int ks = 0; ks < 2; ks++) {
            s16x8 af[WM], bf[WN];
            #pragma unroll
            for (int fi = 0; fi < WM; fi++) {
                af[fi] = *(const s16x8*)(aB + (ks * 2 * WM + wm * WM + fi) * 1024);
                unsigned km = (dx == 0) ? 0xFFFFFFFFu : ((dx < 0) ? kmL[fi] : kmR[fi]);
                af[fi] = andm(af[fi], km);
            }
            #pragma unroll
            for (int j = 0; j < WN; j++)
                bf[j] = *(const s16x8*)(bB + (ks * 2 * WN + wn * WN + j) * 1024);
            #pragma unroll
            for (int fi = 0; fi < WM; fi++)
                #pragma unroll
                for (int j = 0; j < WN; j++)
                    acc[fi][j] = __builtin_amdgcn_mfma_f32_16x16x32_bf16(
                        af[fi], bf[j], acc[fi][j], 0, 0, 0);
        }
        __syncthreads();
        cur ^= 1;
    }

    // ---- epilogue ----
    int oc_l = lane & 15;
    #pragma unroll
    for (int j = 0; j < WN; j++) {
        int oc = nt * NTILE + (wn * WN + j) * 16 + oc_l;
        float bs = 0.0f;
        if (oc < OCreal) bs = (oc < OC1) ? bias1[oc] : bias2[oc - OC1];
        #pragma unroll
        for (int fi = 0; fi < WM; fi++) {
            int prow = p0 + (wm * WM + fi) * 16 + (lane >> 4) * 4;
            #pragma unroll
            for (int r = 0; r < 4; r++) {
                int p = prow + r;
                if (p >= HWN) continue;
                float vv = acc[fi][j][r] + bs;
                if (ACT == 1) vv = fmaxf(vv, 0.0f);
                else if (ACT == 2) vv = 1.0f / (1.0f + __expf(-vv));
                else if (ACT == 3) vv = tanhf(vv);
                if (EPI == 2) {
                    if (oc < OCreal) fout[((size_t)b * OCreal + oc) * HWN + p] = vv;
                } else {
                    unsigned short bvv = f2b(vv);
                    size_t row = (size_t)b * (OGUARD ? RSTR : HWN) + p;
                    gout[row * OCS + ocoff + oc] = bvv;
                    if (EPI == 1) gout2[((size_t)b * HWN + p) * OCS2 + oc] = bvv;
                }
            }
        }
    }
}

// ---------------------------------------------------------------------------
// flow conv (4->64, 3x3, relu), direct f32, writes guarded gi ch 448..511
// ---------------------------------------------------------------------------
__global__ void flowconv_k(const float* __restrict__ flow0, const float* __restrict__ flow1,
                           const float* __restrict__ w, const float* __restrict__ bias,
                           unsigned short* __restrict__ gi) {
    int n = blockIdx.x * 64 + threadIdx.x;
    int b = blockIdx.y;
    if (n >= HWN) return;
    int y = n / WW, x = n - y * WW;
    float v[36];
    for (int c = 0; c < 4; c++) {
        const float* pl = (c < 2) ? flow0 + ((size_t)b * 2 + c) * HWN
                                  : flow1 + ((size_t)b * 2 + (c - 2)) * HWN;
        #pragma unroll
        for (int dy = -1; dy <= 1; dy++)
            #pragma unroll
            for (int dx = -1; dx <= 1; dx++) {
                int yy = y + dy, xx = x + dx;
                v[c * 9 + (dy + 1) * 3 + (dx + 1)] =
                    (((unsigned)yy < (unsigned)HH) && ((unsigned)xx < (unsigned)WW))
                        ? pl[(size_t)yy * WW + xx] : 0.0f;
            }
    }
    unsigned short* op = gi + ((size_t)b * RSTR + n) * 512 + 448;
    for (int oc0 = 0; oc0 < 64; oc0 += 8) {
        s16x8 o;
        #pragma unroll
        for (int j = 0; j < 8; j++) {
            int oc = oc0 + j;
            const float* wpp = w + (size_t)oc * 36;
            float a = bias[oc];
            #pragma unroll
            for (int k = 0; k < 36; k++) a += wpp[k] * v[k];
            o[j] = (short)f2b(fmaxf(a, 0.0f));
        }
        *(s16x8*)(op + oc0) = o;
    }
}

// ---------------------------------------------------------------------------
// rh: guarded gi[ch 0..191] = r * h
// ---------------------------------------------------------------------------
__global__ void rh_k(const unsigned short* __restrict__ zr, const unsigned short* __restrict__ hs,
                     unsigned short* __restrict__ gi) {
    int idx = blockIdx.x * 256 + threadIdx.x;
    if (idx >= BB * HWN * 24) return;
    int n = idx / 24, c8 = (idx % 24) * 8;
    int b = n / HWN, nn = n - b * HWN;
    s16x8 r = *(const s16x8*)(zr + (size_t)n * 384 + 192 + c8);
    s16x8 h = *(const s16x8*)(hs + (size_t)n * 192 + c8);
    s16x8 o;
    #pragma unroll
    for (int j = 0; j < 8; j++)
        o[j] = (short)f2b(b2f((unsigned short)r[j]) * b2f((unsigned short)h[j]));
    *(s16x8*)(gi + ((size_t)b * RSTR + nn) * 512 + c8) = o;
}

// ---------------------------------------------------------------------------
// hnew: guarded gi[ch 0..191] = (1-z)*h + z*q
// ---------------------------------------------------------------------------
__global__ void hnew_k(const unsigned short* __restrict__ zr, const unsigned short* __restrict__ hs,
                       const unsigned short* __restrict__ q, unsigned short* __restrict__ gi) {
    int idx = blockIdx.x * 256 + threadIdx.x;
    if (idx >= BB * HWN * 24) return;
    int n = idx / 24, c8 = (idx % 24) * 8;
    int b = n / HWN, nn = n - b * HWN;
    s16x8 z = *(const s16x8*)(zr + (size_t)n * 384 + c8);
    s16x8 h = *(const s16x8*)(hs + (size_t)n * 192 + c8);
    s16x8 qq = *(const s16x8*)(q + (size_t)n * 192 + c8);
    s16x8 o;
    #pragma unroll
    for (int j = 0; j < 8; j++) {
        float zf = b2f((unsigned short)z[j]);
        o[j] = (short)f2b((1.0f - zf) * b2f((unsigned short)h[j]) + zf * b2f((unsigned short)qq[j]));
    }
    *(s16x8*)(gi + ((size_t)b * RSTR + nn) * 512 + c8) = o;
}

// ---------------------------------------------------------------------------
extern "C" void kernel_launch(void* const* d_in, const int* in_sizes, int n_in,
                              void* d_out, int out_size, void* d_ws, size_t ws_size,
                              hipStream_t stream) {
    const float* fmap0 = (const float*)d_in[0];
    const float* fmap1 = (const float*)d_in[1];
    const float* ft    = (const float*)d_in[2];
    const float* flow0 = (const float*)d_in[3];
    const float* flow1 = (const float*)d_in[4];
    const float* embt  = (const float*)d_in[5];
    const float* w_corr = (const float*)d_in[6];
    const float* b_corr = (const float*)d_in[7];
    const float* w_flow = (const float*)d_in[8];
    const float* b_flow = (const float*)d_in[9];
    const float* w_ctx  = (const float*)d_in[10];
    const float* b_ctx  = (const float*)d_in[11];
    const float* w_z    = (const float*)d_in[12];
    const float* b_z    = (const float*)d_in[13];
    const float* w_r    = (const float*)d_in[14];
    const float* b_r    = (const float*)d_in[15];
    const float* w_q    = (const float*)d_in[16];
    const float* b_q    = (const float*)d_in[17];
    const float* w_fh   = (const float*)d_in[18];
    const float* b_fh   = (const float*)d_in[19];
    const float* w_dh   = (const float*)d_in[20];
    const float* b_dh   = (const float*)d_in[21];
    float* out = (float*)d_out;

    char* ws = (char*)d_ws;
    size_t off = 0;
    auto alloc = [&](size_t bytes) { size_t o = off; off += (bytes + 255) & ~(size_t)255; return o; };

    const size_t GROWS = (size_t)GR + (size_t)BB * RSTR;

    float* f0cl = (float*)(ws + alloc((size_t)BB * HWN * CC * 4));
    float* f1cl = (float*)(ws + alloc((size_t)BB * HWN * CC * 4));
    float* f0p1 = (float*)(ws + alloc((size_t)BB * 30 * 54 * CC * 4));
    float* f0p2 = (float*)(ws + alloc((size_t)BB * 15 * 27 * CC * 4));
    float* f0p3 = (float*)(ws + alloc((size_t)BB * 7 * 13 * CC * 4));
    float* f1p1 = (float*)(ws + alloc((size_t)BB * 30 * 54 * CC * 4));
    float* f1p2 = (float*)(ws + alloc((size_t)BB * 15 * 27 * CC * 4));
    float* f1p3 = (float*)(ws + alloc((size_t)BB * 7 * 13 * CC * 4));
    unsigned short* ftcl   = (unsigned short*)(ws + alloc(GROWS * 128 * 2));
    unsigned short* corrcl = (unsigned short*)(ws + alloc(GROWS * 416 * 2));
    unsigned short* gi     = (unsigned short*)(ws + alloc(GROWS * 512 * 2));
    unsigned short* hsep   = (unsigned short*)(ws + alloc((size_t)BB * HWN * 192 * 2));
    unsigned short* zrbuf  = (unsigned short*)(ws + alloc((size_t)BB * HWN * 384 * 2));
    unsigned short* qbuf   = (unsigned short*)(ws + alloc((size_t)BB * HWN * 192 * 2));
    // packed weights (fragment-linear blocks), chunk counts x 16B
    unsigned short* wpzr   = (unsigned short*)(ws + alloc((size_t)9 * 8 * 3 * 16 * 64 * 16));
    unsigned short* wpq    = (unsigned short*)(ws + alloc((size_t)9 * 8 * 2 * 12 * 64 * 16));
    unsigned short* wpctx  = (unsigned short*)(ws + alloc((size_t)9 * 2 * 2 * 12 * 64 * 16));
    unsigned short* wpdh   = (unsigned short*)(ws + alloc((size_t)9 * 3 * 1 * 16 * 64 * 16));
    unsigned short* wpcorr = (unsigned short*)(ws + alloc((size_t)1 * 7 * 2 * 16 * 64 * 16));

    unsigned short* ftclG   = ftcl   + (size_t)GR * 128;
    unsigned short* corrclG = corrcl + (size_t)GR * 416;
    unsigned short* giG     = gi     + (size_t)GR * 512;

    // zero guard rows
    zero_guard_k<<<dim3(((BB + 1) * GR * (512 / 8) + 255) / 256), dim3(256), 0, stream>>>(gi, 512);
    zero_guard_k<<<dim3(((BB + 1) * GR * (128 / 8) + 255) / 256), dim3(256), 0, stream>>>(ftcl, 128);
    zero_guard_k<<<dim3(((BB + 1) * GR * (416 / 8) + 255) / 256), dim3(256), 0, stream>>>(corrcl, 416);

    // weight packing (fragment-linear)
    packw2_k<<<dim3((9 * 8 * 3 * 16 * 64 + 255) / 256), dim3(256), 0, stream>>>(
        w_z, w_r, 192, 384, 512, 9, 8, 3, 16, 128, wpzr);
    packw2_k<<<dim3((9 * 8 * 2 * 12 * 64 + 255) / 256), dim3(256), 0, stream>>>(
        w_q, w_q, 192, 192, 512, 9, 8, 2, 12, 96, wpq);
    packw2_k<<<dim3((9 * 2 * 2 * 12 * 64 + 255) / 256), dim3(256), 0, stream>>>(
        w_ctx, w_ctx, 192, 192, 112, 9, 2, 2, 12, 96, wpctx);
    packw2_k<<<dim3((9 * 3 * 1 * 16 * 64 + 255) / 256), dim3(256), 0, stream>>>(
        w_dh, w_fh, 112, 116, 192, 9, 3, 1, 16, 128, wpdh);
    packw2_k<<<dim3((1 * 7 * 2 * 16 * 64 + 255) / 256), dim3(256), 0, stream>>>(
        w_corr, w_corr, 256, 256, 392, 1, 7, 2, 16, 128, wpcorr);

    // channel-last transposes + pyramids
    f2cl_k<<<dim3((HWN + 63) / 64, BB), dim3(64), 0, stream>>>(fmap0, f0cl);
    f2cl_k<<<dim3((HWN + 63) / 64, BB), dim3(64), 0, stream>>>(fmap1, f1cl);
    ft2cl_k<<<dim3((HWN + 63) / 64, BB), dim3(64), 0, stream>>>(ft, ftclG);
    pool_k<<<dim3(BB * 30 * 54), dim3(128), 0, stream>>>(f0cl, f0p1, 60, 108, 30, 54);
    pool_k<<<dim3(BB * 15 * 27), dim3(128), 0, stream>>>(f0p1, f0p2, 30, 54, 15, 27);
    pool_k<<<dim3(BB * 7 * 13),  dim3(128), 0, stream>>>(f0p2, f0p3, 15, 27, 7, 13);
    pool_k<<<dim3(BB * 30 * 54), dim3(128), 0, stream>>>(f1cl, f1p1, 60, 108, 30, 54);
    pool_k<<<dim3(BB * 15 * 27), dim3(128), 0, stream>>>(f1p1, f1p2, 30, 54, 15, 27);
    pool_k<<<dim3(BB * 7 * 13),  dim3(128), 0, stream>>>(f1p2, f1p3, 15, 27, 7, 13);

    // lookup -> guarded corr_cl bf16
    lookup_k<<<dim3(BB * HWN, 2), dim3(256), 0, stream>>>(
        f0cl, f1cl, f0p1, f0p2, f0p3, f1p1, f1p2, f1p3,
        flow0, flow1, embt, corrclG);

    // ffeat -> giG ch 448..511
    flowconv_k<<<dim3((HWN + 63) / 64, BB), dim3(64), 0, stream>>>(flow0, flow1, w_flow, b_flow, giG);

    // cfeat = relu(1x1 conv corrcl) -> giG ch 192..447   (64x128 tile, NNT=2)
    convg_k<2, 4, 1, 7, 416, 2, 1, 0, 1><<<dim3(102, 2, BB), dim3(256), 0, stream>>>(
        corrclG, wpcorr, b_corr, b_corr, 256, 256, giG, 512, 192, nullptr, 0, nullptr);

    // h = tanh(ctx conv ftcl) -> giG ch 0..191 AND hsep  (64x96 tile, NNT=2)
    convg_k<2, 3, 9, 2, 128, 2, 3, 1, 1><<<dim3(102, 2, BB), dim3(256), 0, stream>>>(
        ftclG, wpctx, b_ctx, b_ctx, 192, 192, giG, 512, 0, hsep, 192, nullptr);

    // z|r = sigmoid(conv gi) -> zrbuf [B][HW][384]       (64x128 tile, NNT=3)
    convg_k<2, 4, 9, 8, 512, 3, 2, 0, 0><<<dim3(102, 3, BB), dim3(256), 0, stream>>>(
        giG, wpzr, b_z, b_r, 192, 384, zrbuf, 384, 0, nullptr, 0, nullptr);

    // giG ch0..191 = r*h
    rh_k<<<dim3((BB * HWN * 24 + 255) / 256), dim3(256), 0, stream>>>(zrbuf, hsep, giG);

    // q = tanh(conv gi) -> qbuf                          (64x96 tile, NNT=2)
    convg_k<2, 3, 9, 8, 512, 2, 3, 0, 0><<<dim3(102, 2, BB), dim3(256), 0, stream>>>(
        giG, wpq, b_q, b_q, 192, 192, qbuf, 192, 0, nullptr, 0, nullptr);

    // giG ch0..191 = (1-z)h + z q
    hnew_k<<<dim3((BB * HWN * 24 + 255) / 256), dim3(256), 0, stream>>>(zrbuf, hsep, qbuf, giG);

    // out = [dh(112); fh(4)] conv of h' -> f32 CF        (64x128 tile, NNT=1)
    convg_k<2, 4, 9, 3, 512, 1, 0, 2, 0><<<dim3(102, 1, BB), dim3(256), 0, stream>>>(
        giG, wpdh, b_dh, b_fh, 112, 116, nullptr, 0, 0, nullptr, 0, out);
}